// Round 3
// baseline (480.097 us; speedup 1.0000x reference)
//
#include <hip/hip_runtime.h>

// Vector quantizer, bit-exact emulation of the numpy-f32 reference pipeline:
//   Sx[n] = np.sum(x_flat*x_flat, 1)   (numpy pairwise_sum, n=256)
//   M     = (2*x_flat) @ cb.T          (BLAS: sequential FMA over c ascending)
//   dist  = fl(fl(Sx - M) + Se),  idx = argmin (first min)
// x (16,256,1500) f32, codebook (2048,256) f32.
// out = [quantized (B,C,T) | indices (B,1,T) as float | loss] f32.

#define B_DIM 16
#define C_DIM 256
#define T_DIM 1500
#define K_CODES 2048
#define N_ROWS (B_DIM * T_DIM)               // 24000
#define TOTAL_ELEMS (B_DIM * C_DIM * T_DIM)  // 6144000

#define TM 32       // t-rows per argmin block
#define TKC 256     // codes per chunk
#define CS 32       // c per step
#define OT 64       // t per output block

// ---------------- kernel A: Se[k] = np-pairwise sum of cb row squares -------
__global__ __launch_bounds__(256) void vq_se(const float* __restrict__ cb,
                                             float* __restrict__ Se) {
    const int k = blockIdx.x * 256 + threadIdx.x;
    if (k >= K_CODES) return;
    const float* row = cb + (size_t)k * C_DIM;
    float h[2];
#pragma unroll
    for (int half = 0; half < 2; ++half) {
        const float* a = row + half * 128;
        float r[8];
#pragma unroll
        for (int j = 0; j < 8; ++j) r[j] = __fmul_rn(a[j], a[j]);
        for (int i = 8; i < 128; i += 8)
#pragma unroll
            for (int j = 0; j < 8; ++j)
                r[j] = __fadd_rn(r[j], __fmul_rn(a[i + j], a[i + j]));
        h[half] = __fadd_rn(
            __fadd_rn(__fadd_rn(r[0], r[1]), __fadd_rn(r[2], r[3])),
            __fadd_rn(__fadd_rn(r[4], r[5]), __fadd_rn(r[6], r[7])));
    }
    Se[k] = __fadd_rn(h[0], h[1]);
}

// ---------------- kernel B: Sx[n] = np-pairwise sum of x row squares --------
__global__ __launch_bounds__(256) void vq_sx(const float* __restrict__ x,
                                             float* __restrict__ Sx) {
    const int n = blockIdx.x * 256 + threadIdx.x;
    if (n >= N_ROWS) return;
    const int b = n / T_DIM, t = n - b * T_DIM;
    const float* base = x + (size_t)b * C_DIM * T_DIM + t;
    float h[2];
#pragma unroll
    for (int half = 0; half < 2; ++half) {
        float r[8];
#pragma unroll
        for (int j = 0; j < 8; ++j) {
            const float v = base[(size_t)(half * 128 + j) * T_DIM];
            r[j] = __fmul_rn(v, v);
        }
        for (int i = 8; i < 128; i += 8)
#pragma unroll
            for (int j = 0; j < 8; ++j) {
                const float v = base[(size_t)(half * 128 + i + j) * T_DIM];
                r[j] = __fadd_rn(r[j], __fmul_rn(v, v));
            }
        h[half] = __fadd_rn(
            __fadd_rn(__fadd_rn(r[0], r[1]), __fadd_rn(r[2], r[3])),
            __fadd_rn(__fadd_rn(r[4], r[5]), __fadd_rn(r[6], r[7])));
    }
    Sx[n] = __fadd_rn(h[0], h[1]);
}

// ---------------- kernel C: fused GEMM + argmin (bit-exact np-f32) ----------
// block: 256 threads. tile: 32 t-rows x 256-code chunk, C ascending in steps
// of 32. thread (tr=tid&7, tcol=tid>>3): micro-tile 4 rows x 8 codes. Each
// acc chain applies fmaf over c = 0..255 strictly ascending (matches BLAS).
// LDS XOR-granule swizzle (self-inverting on read) keeps ds_read_b128
// conflict-free.
__global__ __launch_bounds__(256) void vq_argmin(
    const float* __restrict__ x, const float* __restrict__ cb,
    const float* __restrict__ Se, const float* __restrict__ Sx,
    int* __restrict__ idxws) {
    __shared__ float xs[TM * CS];     // [r][granule ^ (r>>2)]
    __shared__ float cs[TKC * CS];    // [kk][granule ^ ((kk>>3)&7)]
    __shared__ float e2s[TKC];
    __shared__ float Sxs[TM];

    const int tid = threadIdx.x;
    const int b = blockIdx.y;
    const int t0 = blockIdx.x * TM;

    const int tr = tid & 7;
    const int tcol = tid >> 3;

    if (tid < TM) {
        const int t = t0 + tid;
        Sxs[tid] = (t < T_DIM) ? Sx[b * T_DIM + t] : 0.f;
    }

    float m1[4];
    int k1r[4];
#pragma unroll
    for (int i = 0; i < 4; ++i) { m1[i] = 1e30f; k1r[i] = 0; }

    for (int kc = 0; kc < K_CODES; kc += TKC) {
        __syncthreads();                       // protect e2s/Sxs from prev use
        e2s[tid] = Se[kc + tid];

        float acc[4][8];
#pragma unroll
        for (int i = 0; i < 4; ++i)
#pragma unroll
            for (int j = 0; j < 8; ++j) acc[i][j] = 0.f;

        for (int c0 = 0; c0 < C_DIM; c0 += CS) {
            __syncthreads();                   // prev compute done before overwrite
            // ---- X tile: 32 t x 32 c, float4 along t, scalar scatter to LDS
            {
                const int tq = tid & 7;
                const int ci = tid >> 3;       // 0..31
                const int t = t0 + tq * 4;
                float4 v = make_float4(0.f, 0.f, 0.f, 0.f);
                if (t < T_DIM)
                    v = *reinterpret_cast<const float4*>(
                        x + (size_t)(b * C_DIM + c0 + ci) * T_DIM + t);
                const int gc = ci >> 2, w = ci & 3;
                const int swg = ((gc ^ tq) << 2) | w;
#pragma unroll
                for (int q = 0; q < 4; ++q)
                    xs[(tq * 4 + q) * CS + swg] = (&v.x)[q];
            }
            // ---- CB tile: 256 codes x 32 c, float4 all the way
            {
#pragma unroll
                for (int p = 0; p < 8; ++p) {
                    const int id = tid + (p << 8);   // float4 id 0..2047
                    const int kk = id >> 3;
                    const int g4 = id & 7;
                    const float4 v = *reinterpret_cast<const float4*>(
                        cb + (size_t)(kc + kk) * C_DIM + c0 + g4 * 4);
                    *reinterpret_cast<float4*>(
                        &cs[kk * CS + ((g4 ^ ((kk >> 3) & 7)) << 2)]) = v;
                }
            }
            __syncthreads();
            // ---- compute: c ascending within chunk (granule g, then .x.y.z.w)
#pragma unroll
            for (int g = 0; g < 8; ++g) {
                float4 xv[4];
#pragma unroll
                for (int i = 0; i < 4; ++i)
                    xv[i] = *reinterpret_cast<const float4*>(
                        &xs[(tr * 4 + i) * CS + ((g ^ tr) << 2)]);
#pragma unroll
                for (int j = 0; j < 8; ++j) {
                    const int kk = tcol * 8 + j;
                    const float4 cv = *reinterpret_cast<const float4*>(
                        &cs[kk * CS + ((g ^ (tcol & 7)) << 2)]);
#pragma unroll
                    for (int i = 0; i < 4; ++i) {
                        acc[i][j] = fmaf(xv[i].x, cv.x, acc[i][j]);
                        acc[i][j] = fmaf(xv[i].y, cv.y, acc[i][j]);
                        acc[i][j] = fmaf(xv[i].z, cv.z, acc[i][j]);
                        acc[i][j] = fmaf(xv[i].w, cv.w, acc[i][j]);
                    }
                }
            }
        }
        // ---- score: dist = fl(fl(Sx - 2*M) + Se); first-min (k ascending)
#pragma unroll
        for (int j = 0; j < 8; ++j) {
            const int kk = tcol * 8 + j;
            const float ev = e2s[kk];
            const int kglob = kc + kk;
#pragma unroll
            for (int i = 0; i < 4; ++i) {
                const float twoM = __fmul_rn(2.0f, acc[i][j]);
                const float s = __fadd_rn(__fsub_rn(Sxs[tr * 4 + i], twoM), ev);
                if (s < m1[i]) { m1[i] = s; k1r[i] = kglob; }
            }
        }
    }

    // ---- cross-thread argmin merge (32 threads share each row), alias cs
    __syncthreads();
    float* redm1 = cs;
    int* redk1 = reinterpret_cast<int*>(cs + TM * 32);
#pragma unroll
    for (int i = 0; i < 4; ++i) {
        const int r = tr * 4 + i;
        redm1[r * 32 + tcol] = m1[i];
        redk1[r * 32 + tcol] = k1r[i];
    }
    __syncthreads();
    if (tid < TM) {
        const int r = tid;
        float bm1 = 1e30f;
        int bk = 0x7fffffff;
        for (int tc = 0; tc < 32; ++tc) {
            const float c1 = redm1[r * 32 + tc];
            const int ck = redk1[r * 32 + tc];
            if (c1 < bm1 || (c1 == bm1 && ck < bk)) { bm1 = c1; bk = ck; }
        }
        const int t = t0 + r;
        if (t < T_DIM) idxws[b * T_DIM + t] = bk;
    }
}

// ---------------- kernel D: gather + STE output + indices + loss partials ---
__global__ __launch_bounds__(256) void vq_output(
    const float* __restrict__ x, const float* __restrict__ cb,
    const int* __restrict__ idxws, float* __restrict__ out,
    float* __restrict__ partials) {
    const int tid = threadIdx.x;
    const int b = blockIdx.y;
    const int t0 = blockIdx.x * OT;
    __shared__ int idxs[OT];
    if (tid < OT) {
        const int t = t0 + tid;
        if (t < T_DIM) {
            const int id = idxws[b * T_DIM + t];
            idxs[tid] = id;
            out[(size_t)TOTAL_ELEMS + b * T_DIM + t] = (float)id;   // indices
        }
    }
    __syncthreads();
    const int ti = tid & 63;
    const int cq = tid >> 6;       // 0..3
    const int t = t0 + ti;
    float lsum = 0.f;
    if (t < T_DIM) {
        const int id = idxs[ti];
        for (int c0 = 0; c0 < C_DIM; c0 += 4) {
            const int c = c0 + cq;
            const size_t off = (size_t)(b * C_DIM + c) * T_DIM + t;
            const float xv = x[off];
            const float q = cb[(size_t)id * C_DIM + c];
            out[off] = __fadd_rn(xv, __fsub_rn(q, xv));   // STE, np-exact
            const float d = __fsub_rn(q, xv);
            lsum = fmaf(d, d, lsum);
        }
    }
#pragma unroll
    for (int off = 32; off; off >>= 1) lsum += __shfl_down(lsum, off, 64);
    __shared__ float wsum[4];
    if ((tid & 63) == 0) wsum[tid >> 6] = lsum;
    __syncthreads();
    if (tid == 0)
        partials[blockIdx.y * gridDim.x + blockIdx.x] =
            wsum[0] + wsum[1] + wsum[2] + wsum[3];
}

// ---------------- kernel E: final loss reduce -------------------------------
__global__ void vq_loss(const float* __restrict__ partials, int nparts,
                        float* __restrict__ out) {
    __shared__ float red[256];
    float s = 0.f;
    for (int i = threadIdx.x; i < nparts; i += 256) s += partials[i];
    red[threadIdx.x] = s;
    __syncthreads();
    for (int off = 128; off; off >>= 1) {
        if (threadIdx.x < off) red[threadIdx.x] += red[threadIdx.x + off];
        __syncthreads();
    }
    if (threadIdx.x == 0)
        out[(size_t)TOTAL_ELEMS + N_ROWS] = red[0] * (1.0f / (float)TOTAL_ELEMS);
}

// ---------------- launch -----------------------------------------------------
extern "C" void kernel_launch(void* const* d_in, const int* in_sizes, int n_in,
                              void* d_out, int out_size, void* d_ws, size_t ws_size,
                              hipStream_t stream) {
    const float* x = (const float*)d_in[0];
    const float* cb = (const float*)d_in[1];
    float* out = (float*)d_out;

    // ws (4B words): Se[2048] | Sx[24000] | idx[24000] | partials[384]
    float* Se = (float*)d_ws;
    float* Sx = Se + K_CODES;
    int* idxws = (int*)d_ws + K_CODES + N_ROWS;
    float* partials = (float*)d_ws + K_CODES + 2 * N_ROWS;

    vq_se<<<dim3((K_CODES + 255) / 256), dim3(256), 0, stream>>>(cb, Se);
    vq_sx<<<dim3((N_ROWS + 255) / 256), dim3(256), 0, stream>>>(x, Sx);
    vq_argmin<<<dim3((T_DIM + TM - 1) / TM, B_DIM), dim3(256), 0, stream>>>(
        x, cb, Se, Sx, idxws);
    vq_output<<<dim3((T_DIM + OT - 1) / OT, B_DIM), dim3(256), 0, stream>>>(
        x, cb, idxws, out, partials);
    vq_loss<<<dim3(1), dim3(256), 0, stream>>>(
        partials, (T_DIM + OT - 1) / OT * B_DIM, out);
}

// Round 4
// 387.198 us; speedup vs baseline: 1.2399x; 1.2399x over previous
//
#include <hip/hip_runtime.h>
#include <stdint.h>

// Vector quantizer, bit-exact emulation of the numpy-f32 reference pipeline:
//   Sx[n] = np.sum(x_flat*x_flat, 1)   (numpy pairwise_sum, n=256)
//   M     = x_flat @ cb.T              (BLAS: sequential FMA over c ascending)
//   dist  = fl(fl(Sx - 2M) + Se),  idx = argmin (first min)
// x (16,256,1500) f32, codebook (2048,256) f32.
// out = [quantized (B,C,T) | indices (B,1,T) as float | loss] f32.
//
// Perf structure: xT = transpose(x) staged in the d_out scratch region;
// fused GEMM+argmin with 64-row x 256-code tiles, 8x8 micro-tile,
// global_load_lds(16B) staging with pre-swizzled sources (linear LDS dest,
// XOR-swizzled conflict-free ds_read_b128), K split 4-ways across blocks,
// merged via u64 (dist_bits<<32 | k) atomicMin.

#define B_DIM 16
#define C_DIM 256
#define T_DIM 1500
#define K_CODES 2048
#define N_ROWS (B_DIM * T_DIM)               // 24000
#define TOTAL_ELEMS (B_DIM * C_DIM * T_DIM)  // 6144000

#define TM 64        // t-rows per argmin block
#define TKC 256      // codes per chunk
#define CS 32        // c per step
#define KSLICE 512   // codes per block (4 slices)
#define OT 64        // t per output block

__device__ __forceinline__ void gl_lds16(const float* g, float* l) {
    __builtin_amdgcn_global_load_lds(
        (const __attribute__((address_space(1))) void*)(uintptr_t)g,
        (__attribute__((address_space(3))) void*)(uintptr_t)l, 16, 0, 0);
}

// ---------------- kernel T: x (B,C,T) -> xT (B,T,C) in d_out scratch --------
__global__ __launch_bounds__(256) void vq_transpose(const float* __restrict__ x,
                                                    float* __restrict__ xT) {
    __shared__ float tile[32][33];
    const int b = blockIdx.z;
    const int t0 = blockIdx.x * 32;
    const int c0 = blockIdx.y * 32;
    const int tx = threadIdx.x & 31;
    const int ty = threadIdx.x >> 5;          // 0..7
#pragma unroll
    for (int q = 0; q < 4; ++q) {
        const int c = c0 + ty * 4 + q;
        int t = t0 + tx; if (t >= T_DIM) t = T_DIM - 1;
        tile[ty * 4 + q][tx] = x[((size_t)b * C_DIM + c) * T_DIM + t];
    }
    __syncthreads();
#pragma unroll
    for (int q = 0; q < 4; ++q) {
        const int t = t0 + ty * 4 + q;
        if (t < T_DIM)
            xT[((size_t)b * T_DIM + t) * C_DIM + c0 + tx] = tile[tx][ty * 4 + q];
    }
}

// ---------------- kernel A: Se[k] = np-pairwise sum of cb row squares -------
__global__ __launch_bounds__(256) void vq_se(const float* __restrict__ cb,
                                             float* __restrict__ Se) {
    const int k = blockIdx.x * 256 + threadIdx.x;
    if (k >= K_CODES) return;
    const float* row = cb + (size_t)k * C_DIM;
    float h[2];
#pragma unroll
    for (int half = 0; half < 2; ++half) {
        const float* a = row + half * 128;
        float r[8];
#pragma unroll
        for (int j = 0; j < 8; ++j) r[j] = __fmul_rn(a[j], a[j]);
        for (int i = 8; i < 128; i += 8)
#pragma unroll
            for (int j = 0; j < 8; ++j)
                r[j] = __fadd_rn(r[j], __fmul_rn(a[i + j], a[i + j]));
        h[half] = __fadd_rn(
            __fadd_rn(__fadd_rn(r[0], r[1]), __fadd_rn(r[2], r[3])),
            __fadd_rn(__fadd_rn(r[4], r[5]), __fadd_rn(r[6], r[7])));
    }
    Se[k] = __fadd_rn(h[0], h[1]);
}

// ---------------- kernel B: Sx[n] from xT rows (same pairwise order) --------
__global__ __launch_bounds__(256) void vq_sx(const float* __restrict__ xT,
                                             float* __restrict__ Sx) {
    const int n = blockIdx.x * 256 + threadIdx.x;
    if (n >= N_ROWS) return;
    const float* row = xT + (size_t)n * C_DIM;
    float h[2];
#pragma unroll
    for (int half = 0; half < 2; ++half) {
        const float* a = row + half * 128;
        float r[8];
#pragma unroll
        for (int j = 0; j < 8; ++j) r[j] = __fmul_rn(a[j], a[j]);
        for (int i = 8; i < 128; i += 8)
#pragma unroll
            for (int j = 0; j < 8; ++j)
                r[j] = __fadd_rn(r[j], __fmul_rn(a[i + j], a[i + j]));
        h[half] = __fadd_rn(
            __fadd_rn(__fadd_rn(r[0], r[1]), __fadd_rn(r[2], r[3])),
            __fadd_rn(__fadd_rn(r[4], r[5]), __fadd_rn(r[6], r[7])));
    }
    Sx[n] = __fadd_rn(h[0], h[1]);
}

// ---------------- kernel I: init u64 argmin slots ---------------------------
__global__ void vq_init(unsigned long long* __restrict__ slots) {
    const int n = blockIdx.x * 256 + threadIdx.x;
    if (n < N_ROWS) slots[n] = ~0ull;
}

// ---------------- kernel C: fused GEMM + argmin (bit-exact np-f32) ----------
// grid (24 t-tiles, 16 b, 4 k-slices), 256 threads.
// thread (tr=tid&7, tcol=tid>>3): micro-tile 8 rows x 8 codes.
// LDS layout: row-major with slot s holding logical granule g4 = s ^ ((row>>3)&7)
// (self-inverting XOR). global_load_lds writes linear LDS, source pre-swizzled.
__global__ __launch_bounds__(256) void vq_argmin(
    const float* __restrict__ xT, const float* __restrict__ cb,
    const float* __restrict__ Se, const float* __restrict__ Sx,
    unsigned long long* __restrict__ slots) {
    __shared__ float xs[TM * CS];        // 8 KB
    __shared__ float cs[TKC * CS];       // 32 KB
    __shared__ float e2s[TKC];
    __shared__ float Sxs[TM];

    const int tid = threadIdx.x;
    const int t0 = blockIdx.x * TM;
    const int b = blockIdx.y;
    const int k0 = blockIdx.z * KSLICE;
    const int tr = tid & 7;
    const int tcol = tid >> 3;           // 0..31

    if (tid < TM) {
        int t = t0 + tid;
        Sxs[tid] = (t < T_DIM) ? Sx[b * T_DIM + t] : 0.f;
    }

    float m1[8];
    int k1[8];
#pragma unroll
    for (int i = 0; i < 8; ++i) { m1[i] = 1e30f; k1[i] = 0x7fffffff; }

    const float* xTb = xT + (size_t)b * T_DIM * C_DIM;

    for (int kc = 0; kc < KSLICE; kc += TKC) {
        __syncthreads();                 // prev chunk fully done (e2s safe)
        e2s[tid] = Se[k0 + kc + tid];

        float acc[8][8];
#pragma unroll
        for (int i = 0; i < 8; ++i)
#pragma unroll
            for (int j = 0; j < 8; ++j) acc[i][j] = 0.f;

        for (int c0 = 0; c0 < C_DIM; c0 += CS) {
            __syncthreads();             // prev step compute done
            // ---- X tile: 64 rows x 32 c = 512 float4, 2 gload_lds per thread
#pragma unroll
            for (int p = 0; p < 2; ++p) {
                const int A = p * 256 + tid;         // linear float4 index
                const int r = A >> 3, slot = A & 7;
                const int g4 = slot ^ ((r >> 3) & 7);
                int t = t0 + r; if (t >= T_DIM) t = T_DIM - 1;   // pad rows dup
                gl_lds16(xTb + (size_t)t * C_DIM + c0 + g4 * 4, &xs[A * 4]);
            }
            // ---- CB tile: 256 rows x 32 c = 2048 float4, 8 per thread
#pragma unroll
            for (int i = 0; i < 8; ++i) {
                const int A = i * 256 + tid;
                const int kk = A >> 3, slot = A & 7;
                const int g4 = slot ^ ((kk >> 3) & 7);
                gl_lds16(cb + (size_t)(k0 + kc + kk) * C_DIM + c0 + g4 * 4,
                         &cs[A * 4]);
            }
            __syncthreads();             // compiler drains vmcnt before barrier
            // ---- compute: c strictly ascending (g, then .x.y.z.w)
#pragma unroll
            for (int g = 0; g < 8; ++g) {
                float4 cv[8];
#pragma unroll
                for (int j = 0; j < 8; ++j)
                    cv[j] = *reinterpret_cast<const float4*>(
                        &cs[(tcol * 8 + j) * CS + ((g ^ (tcol & 7)) << 2)]);
#pragma unroll
                for (int i = 0; i < 8; ++i) {
                    const float4 xv = *reinterpret_cast<const float4*>(
                        &xs[(tr * 8 + i) * CS + ((g ^ tr) << 2)]);
#pragma unroll
                    for (int j = 0; j < 8; ++j) {
                        acc[i][j] = fmaf(xv.x, cv[j].x, acc[i][j]);
                        acc[i][j] = fmaf(xv.y, cv[j].y, acc[i][j]);
                        acc[i][j] = fmaf(xv.z, cv[j].z, acc[i][j]);
                        acc[i][j] = fmaf(xv.w, cv[j].w, acc[i][j]);
                    }
                }
            }
        }
        // ---- score: dist = fl(fl(Sx - 2*M) + Se); first-min (k ascending)
#pragma unroll
        for (int j = 0; j < 8; ++j) {
            const float ev = e2s[tcol * 8 + j];
            const int kg = k0 + kc + tcol * 8 + j;
#pragma unroll
            for (int i = 0; i < 8; ++i) {
                const float s = __fadd_rn(
                    __fsub_rn(Sxs[tr * 8 + i], __fmul_rn(2.0f, acc[i][j])), ev);
                if (s < m1[i]) { m1[i] = s; k1[i] = kg; }
            }
        }
    }

    // ---- cross-thread merge (32 threads per row), alias cs; u64 atomicMin
    __syncthreads();
    float* redm = cs;                          // 2048 floats
    int* redk = reinterpret_cast<int*>(cs + TM * 32);
#pragma unroll
    for (int i = 0; i < 8; ++i) {
        const int r = tr * 8 + i;
        redm[r * 32 + tcol] = m1[i];
        redk[r * 32 + tcol] = k1[i];
    }
    __syncthreads();
    if (tid < TM) {
        const int r = tid;
        float bm = 1e30f;
        int bk = 0x7fffffff;
        for (int tc = 0; tc < 32; ++tc) {
            const float c1 = redm[r * 32 + tc];
            const int ck = redk[r * 32 + tc];
            if (c1 < bm || (c1 == bm && ck < bk)) { bm = c1; bk = ck; }
        }
        const int t = t0 + r;
        if (t < T_DIM) {
            const unsigned long long pack =
                ((unsigned long long)__float_as_uint(bm) << 32) | (unsigned)bk;
            atomicMin(slots + b * T_DIM + t, pack);
        }
    }
}

// ---------------- kernel D: gather + STE output + indices + loss partials ---
__global__ __launch_bounds__(256) void vq_output(
    const float* __restrict__ x, const float* __restrict__ cb,
    const unsigned long long* __restrict__ slots, float* __restrict__ out,
    float* __restrict__ partials) {
    const int tid = threadIdx.x;
    const int b = blockIdx.y;
    const int t0 = blockIdx.x * OT;
    __shared__ int idxs[OT];
    if (tid < OT) {
        const int t = t0 + tid;
        if (t < T_DIM) {
            const int id = (int)(unsigned)(slots[b * T_DIM + t] & 0xffffffffull);
            idxs[tid] = id;
            out[(size_t)TOTAL_ELEMS + b * T_DIM + t] = (float)id;   // indices
        }
    }
    __syncthreads();
    const int ti = tid & 63;
    const int cq = tid >> 6;       // 0..3
    const int t = t0 + ti;
    float lsum = 0.f;
    if (t < T_DIM) {
        const int id = idxs[ti];
        for (int c0 = 0; c0 < C_DIM; c0 += 4) {
            const int c = c0 + cq;
            const size_t off = (size_t)(b * C_DIM + c) * T_DIM + t;
            const float xv = x[off];
            const float q = cb[(size_t)id * C_DIM + c];
            out[off] = __fadd_rn(xv, __fsub_rn(q, xv));   // STE, np-exact
            const float d = __fsub_rn(q, xv);
            lsum = fmaf(d, d, lsum);
        }
    }
#pragma unroll
    for (int off = 32; off; off >>= 1) lsum += __shfl_down(lsum, off, 64);
    __shared__ float wsum[4];
    if ((tid & 63) == 0) wsum[tid >> 6] = lsum;
    __syncthreads();
    if (tid == 0)
        partials[blockIdx.y * gridDim.x + blockIdx.x] =
            wsum[0] + wsum[1] + wsum[2] + wsum[3];
}

// ---------------- kernel E: final loss reduce -------------------------------
__global__ void vq_loss(const float* __restrict__ partials, int nparts,
                        float* __restrict__ out) {
    __shared__ float red[256];
    float s = 0.f;
    for (int i = threadIdx.x; i < nparts; i += 256) s += partials[i];
    red[threadIdx.x] = s;
    __syncthreads();
    for (int off = 128; off; off >>= 1) {
        if (threadIdx.x < off) red[threadIdx.x] += red[threadIdx.x + off];
        __syncthreads();
    }
    if (threadIdx.x == 0)
        out[(size_t)TOTAL_ELEMS + N_ROWS] = red[0] * (1.0f / (float)TOTAL_ELEMS);
}

// ---------------- launch -----------------------------------------------------
extern "C" void kernel_launch(void* const* d_in, const int* in_sizes, int n_in,
                              void* d_out, int out_size, void* d_ws, size_t ws_size,
                              hipStream_t stream) {
    const float* x = (const float*)d_in[0];
    const float* cb = (const float*)d_in[1];
    float* out = (float*)d_out;

    // xT scratch lives in d_out[0 .. 6144000) (overwritten by vq_output later)
    float* xT = out;

    // ws layout (bytes): Se 8K | Sx 96000 | slots (u64, 8-aligned) | partials
    float* Se = (float*)d_ws;
    float* Sx = Se + K_CODES;
    unsigned long long* slots =
        (unsigned long long*)((char*)d_ws + ((8192 + 96000 + 7) & ~7ull));
    float* partials = (float*)(slots + N_ROWS);

    vq_transpose<<<dim3(47, 8, B_DIM), dim3(256), 0, stream>>>(x, xT);
    vq_se<<<dim3(K_CODES / 256), dim3(256), 0, stream>>>(cb, Se);
    vq_sx<<<dim3((N_ROWS + 255) / 256), dim3(256), 0, stream>>>(xT, Sx);
    vq_init<<<dim3((N_ROWS + 255) / 256), dim3(256), 0, stream>>>(slots);
    vq_argmin<<<dim3((T_DIM + TM - 1) / TM, B_DIM, K_CODES / KSLICE),
                dim3(256), 0, stream>>>(xT, cb, Se, Sx, slots);
    vq_output<<<dim3((T_DIM + OT - 1) / OT, B_DIM), dim3(256), 0, stream>>>(
        x, cb, slots, out, partials);
    vq_loss<<<dim3(1), dim3(256), 0, stream>>>(
        partials, (T_DIM + OT - 1) / OT * B_DIM, out);
}